// Round 6
// baseline (145.662 us; speedup 1.0000x reference)
//
#include <hip/hip_runtime.h>

#define BS 256
#define HS 512
#define IN_DIM 64
#define OUT_DIM 4

typedef float nfloat4 __attribute__((ext_vector_type(4)));  // native vec for nt builtins

// ---------------------------------------------------------------------------
// Fully fused: one 1024-thread workgroup per batch element b.
//   Phase A: rec[i] = sum_j hidden[b,j]*(w[i,j]+alpha[i,j]*hebb[b,i,j])
//            (16 waves x 32 rows each, float4 loads, shfl reduce -> LDS)
//   Phase B: hactiv = tanh(Wi@x + bi + rec); 6 head reductions in-block;
//            scale[i] = DAout * hactiv[i] -> LDS
//   Phase C: hebb_new[b,i,j] = clip(hebb[b,i,j] + scale[i]*hidden[b,j])
//            re-read of hebb[b] is L3/L2-resident (read in phase A; nt writes
//            don't evict it); nt stores for the 268 MB output stream.
// ---------------------------------------------------------------------------
__global__ __launch_bounds__(1024) void fused_kernel(
    const float* __restrict__ inputs,
    const float* __restrict__ hidden,
    const float* __restrict__ hebb,
    const float* __restrict__ Wi,  const float* __restrict__ bi,
    const float* __restrict__ w,   const float* __restrict__ alpha,
    const float* __restrict__ Wo,  const float* __restrict__ bo,
    const float* __restrict__ Wv,  const float* __restrict__ bv,
    const float* __restrict__ Wda, const float* __restrict__ bda,
    float* __restrict__ activout, float* __restrict__ valueout,
    float* __restrict__ daout,    float* __restrict__ hactiv,
    float* __restrict__ hebb_new)
{
    const int b    = blockIdx.x;
    const int tid  = threadIdx.x;
    const int wave = tid >> 6;
    const int lane = tid & 63;

    __shared__ __align__(16) float sh_hidden[HS];
    __shared__ __align__(16) float sh_in[IN_DIM];
    __shared__ float sh_rec[HS];
    __shared__ float sh_scale[HS];
    __shared__ float red[16][6];
    __shared__ float da_sh;

    // stage hidden[b,:] and inputs[b,:] into LDS
    if (tid < HS / 4)
        ((float4*)sh_hidden)[tid] = ((const float4*)(hidden + (size_t)b * HS))[tid];
    if (tid >= 512 && tid < 512 + IN_DIM / 4)
        ((float4*)sh_in)[tid - 512] = ((const float4*)(inputs + (size_t)b * IN_DIM))[tid - 512];
    __syncthreads();

    // ---------------- Phase A: rec ----------------
    const float4* __restrict__ hebb4b = (const float4*)(hebb + (size_t)b * HS * HS);
    for (int r = 0; r < 32; ++r) {
        const int i = wave * 32 + r;
        const float4* __restrict__ h4 = hebb4b + i * (HS / 4);
        const float4* __restrict__ w4 = (const float4*)(w     + (size_t)i * HS);
        const float4* __restrict__ a4 = (const float4*)(alpha + (size_t)i * HS);
        float sum = 0.f;
#pragma unroll
        for (int t = 0; t < 2; ++t) {
            const int idx = lane + t * 64;
            const float4 hb = h4[idx];
            const float4 ww = w4[idx];
            const float4 aa = a4[idx];
            const float4 hh = ((const float4*)sh_hidden)[idx];
            sum += hh.x * (ww.x + aa.x * hb.x);
            sum += hh.y * (ww.y + aa.y * hb.y);
            sum += hh.z * (ww.z + aa.z * hb.z);
            sum += hh.w * (ww.w + aa.w * hb.w);
        }
#pragma unroll
        for (int off = 32; off > 0; off >>= 1)
            sum += __shfl_xor(sum, off, 64);
        if (lane == 0) sh_rec[i] = sum;
    }
    __syncthreads();

    // ---------------- Phase B: activations + heads ----------------
    float h = 0.f;
    float p[6] = {0.f, 0.f, 0.f, 0.f, 0.f, 0.f};
    if (tid < HS) {
        float dot = 0.f;
        const float4* __restrict__ wi4 = (const float4*)(Wi + (size_t)tid * IN_DIM);
#pragma unroll
        for (int t = 0; t < IN_DIM / 4; ++t) {
            const float4 a = wi4[t];
            const float4 x = ((const float4*)sh_in)[t];
            dot += a.x * x.x + a.y * x.y + a.z * x.z + a.w * x.w;
        }
        h = tanhf(dot + bi[tid] + sh_rec[tid]);
        hactiv[(size_t)b * HS + tid] = h;
        p[0] = h * Wo[0 * HS + tid];
        p[1] = h * Wo[1 * HS + tid];
        p[2] = h * Wo[2 * HS + tid];
        p[3] = h * Wo[3 * HS + tid];
        p[4] = h * Wv[tid];
        p[5] = h * Wda[tid];
    }
#pragma unroll
    for (int k = 0; k < 6; ++k) {
        float s = p[k];
#pragma unroll
        for (int off = 32; off > 0; off >>= 1)
            s += __shfl_xor(s, off, 64);
        if (lane == 0) red[wave][k] = s;
    }
    __syncthreads();

    if (tid < 6) {
        float s = 0.f;
#pragma unroll
        for (int wv = 0; wv < 16; ++wv) s += red[wv][tid];
        if (tid < 4) {
            activout[b * OUT_DIM + tid] = s + bo[tid];
        } else if (tid == 4) {
            valueout[b] = s + bv[0];
        } else {
            const float da = tanhf(s + bda[0]);
            daout[b] = da;
            da_sh = da;
        }
    }
    __syncthreads();

    if (tid < HS) sh_scale[tid] = da_sh * h;
    __syncthreads();

    // ---------------- Phase C: hebb update ----------------
    nfloat4* __restrict__ dst = (nfloat4*)(hebb_new + (size_t)b * HS * HS);
    for (int r = 0; r < 32; ++r) {
        const int i = wave * 32 + r;
        const float s = sh_scale[i];
#pragma unroll
        for (int t = 0; t < 2; ++t) {
            const int idx = i * (HS / 4) + lane + t * 64;
            const float4 hb = hebb4b[idx];
            const float4 hh = ((const float4*)sh_hidden)[lane + t * 64];
            nfloat4 o;
            o.x = fminf(fmaxf(hb.x + s * hh.x, -1.f), 1.f);
            o.y = fminf(fmaxf(hb.y + s * hh.y, -1.f), 1.f);
            o.z = fminf(fmaxf(hb.z + s * hh.z, -1.f), 1.f);
            o.w = fminf(fmaxf(hb.w + s * hh.w, -1.f), 1.f);
            __builtin_nontemporal_store(o, dst + idx);
        }
    }
}

extern "C" void kernel_launch(void* const* d_in, const int* in_sizes, int n_in,
                              void* d_out, int out_size, void* d_ws, size_t ws_size,
                              hipStream_t stream) {
    const float* inputs = (const float*)d_in[0];
    const float* hidden = (const float*)d_in[1];
    const float* hebb   = (const float*)d_in[2];
    const float* Wi     = (const float*)d_in[3];
    const float* bi     = (const float*)d_in[4];
    const float* w      = (const float*)d_in[5];
    const float* alpha  = (const float*)d_in[6];
    const float* Wo     = (const float*)d_in[7];
    const float* bo     = (const float*)d_in[8];
    const float* Wv     = (const float*)d_in[9];
    const float* bv     = (const float*)d_in[10];
    const float* Wda    = (const float*)d_in[11];
    const float* bda    = (const float*)d_in[12];

    float* out = (float*)d_out;
    float* activout = out;                       // [256,4]   = 1024
    float* valueout = out + 1024;                // [256,1]   = 256
    float* daout    = out + 1280;                // [256,1]   = 256
    float* hactiv   = out + 1536;                // [256,512] = 131072
    float* hebb_new = out + 1536 + BS * HS;      // [256,512,512]

    fused_kernel<<<BS, 1024, 0, stream>>>(inputs, hidden, hebb, Wi, bi, w, alpha,
                                          Wo, bo, Wv, bv, Wda, bda,
                                          activout, valueout, daout, hactiv,
                                          hebb_new);
}